// Round 11
// baseline (690.246 us; speedup 1.0000x reference)
//
#include <hip/hip_runtime.h>

#define H 224
#define W 224
#define HW (H*W)
#define BATCH 2
#define CIN 64
#define COUT 64
#define NOFF 18
#define K576 576          // K = 64 ch * 9 taps
#define KCHUNK 288        // 32 ch * 9 taps per chunk (k = tap*32 + cc)
#define AROW 296          // 288 + 8 bf16 pad (592 B rows, 16B-aligned)
#define OFFS 20           // off LDS stride (18 live, f4-aligned)
#define NBLK (BATCH*HW/32)          // 3136 tiles (4x8 pixels)
#define NB8  (NBLK/8)               // 392 blocks per XCD span
#define TROW 56                     // row-tiles (224/4)
#define TCOL 28                     // col-tiles (224/8)
#define SROW 36                     // staged-patch stride in floats

typedef __attribute__((ext_vector_type(8))) short bf16x8;
typedef __attribute__((ext_vector_type(4))) short s16x4;
typedef __attribute__((ext_vector_type(4))) float f32x4;

__device__ inline short f2bf(float f) {
    unsigned u = __float_as_uint(f);
    u += 0x7FFF + ((u >> 16) & 1);
    return (short)(u >> 16);
}
__device__ inline float bf2f(short h) {
    return __uint_as_float(((unsigned)(unsigned short)h) << 16);
}
__device__ inline void split_bf(float x, short& hi, short& lo) {
    hi = f2bf(x);
    lo = f2bf(x - bf2f(hi));
}
__device__ inline void split_bf4(float a, float b, float c, float d,
                                 s16x4& h4, s16x4& l4) {
    short h0, l0, h1, l1, h2, l2, h3, l3;
    split_bf(a, h0, l0); split_bf(b, h1, l1);
    split_bf(c, h2, l2); split_bf(d, h3, l3);
    h4 = (s16x4){h0, h1, h2, h3};
    l4 = (s16x4){l0, l1, l2, l3};
}
__device__ inline int swizzle_blk(int raw) {
    return (raw & 7) * NB8 + (raw >> 3);
}

// ---------------------------------------------------------------------------
// Weight prep: split into hi/lo bf16, permute K to chunk*288 + tap*32 + cc.
// ---------------------------------------------------------------------------
__global__ __launch_bounds__(256) void k_prepw(const float* __restrict__ wconv,
                                               const float* __restrict__ woff,
                                               short* __restrict__ Wtdh,
                                               short* __restrict__ Wtdl,
                                               short* __restrict__ Wtoh,
                                               short* __restrict__ Wtol) {
    int t = blockIdx.x * 256 + threadIdx.x;
    if (t < COUT * K576) {
        int n = t / K576, kp = t - n * K576;
        int chunk = kp / KCHUNK, r = kp - chunk * KCHUNK;
        int tap = r >> 5, cc = r & 31;
        int c = chunk * 32 + cc;
        short h, l; split_bf(wconv[n * K576 + c * 9 + tap], h, l);
        Wtdh[t] = h; Wtdl[t] = l;
    }
    int t2 = t - COUT * K576;
    if (t2 >= 0 && t2 < 32 * K576) {
        int n = t2 / K576, kp = t2 - n * K576;
        int chunk = kp / KCHUNK, r = kp - chunk * KCHUNK;
        int tap = r >> 5, cc = r & 31;
        int c = chunk * 32 + cc;
        float v = (n < NOFF) ? woff[n * K576 + c * 9 + tap] : 0.0f;
        short h, l; split_bf(v, h, l);
        Wtoh[t2] = h; Wtol[t2] = l;
    }
}

// ---------------------------------------------------------------------------
// x NCHW -> NHWC.
// ---------------------------------------------------------------------------
__global__ __launch_bounds__(256) void k_transpose(const float* __restrict__ x,
                                                   float* __restrict__ xT) {
    __shared__ float Lt[64][65];
    int blk = blockIdx.x, t = threadIdx.x;
    int px0 = blk * 64;
    int b   = px0 / HW;
    int ij0 = px0 - b * HW;
    int lane = t & 63, g = t >> 6;
#pragma unroll
    for (int r = 0; r < 16; ++r) {
        int c = r * 4 + g;
        Lt[c][lane] = x[(b * CIN + c) * HW + ij0 + lane];
    }
    __syncthreads();
#pragma unroll
    for (int r = 0; r < 16; ++r) {
        int px = r * 4 + g;
        xT[((size_t)(b * HW + ij0 + px)) * 64 + lane] = Lt[lane][px];
    }
}

// ---------------------------------------------------------------------------
// FUSED per 4x8 tile: (1) dense 3x3 offset-conv GEMM (N=32, zero-pad via tap
// mask) -> 18 offsets/pixel kept in LDS; (2) deformable sampling from the
// same staged 8x12x32ch patch (border-replicated, rare global fallback);
// (3) deform GEMM (N=64); epilogue stores + fused per-channel stats
// (contiguous 512-B part writes). Split-bf16 everywhere.
// ---------------------------------------------------------------------------
template <bool OUT_NHWC>
__global__ __launch_bounds__(256, 3) void k_fused(const float* __restrict__ xT,
                                                  const short* __restrict__ Wtoh,
                                                  const short* __restrict__ Wtol,
                                                  const float* __restrict__ boff,
                                                  const short* __restrict__ Wtdh,
                                                  const short* __restrict__ Wtdl,
                                                  float* __restrict__ out,
                                                  float* __restrict__ part) {
    // LDS: Ah/Al 37888 | Xs 13824 | offL 2560  = 54272 B (x3 = 162816 <= 160 KiB)
    __shared__ __align__(16) char smem[2 * 32 * AROW * 2 + 96 * SROW * 4 + 32 * OFFS * 4];
    short* Ah   = (short*)smem;
    short* Al   = Ah + 32 * AROW;
    float* Xs   = (float*)(smem + 2 * 32 * AROW * 2);
    float* offL = (float*)(smem + 2 * 32 * AROW * 2 + 96 * SROW * 4);

    const int t    = threadIdx.x;
    const int lane = t & 63;
    const int wave = t >> 6;
    const int vb   = swizzle_blk(blockIdx.x);
    const int b    = vb / (TROW * TCOL);
    const int rem  = vb - b * (TROW * TCOL);
    const int i0   = (rem / TCOL) * 4;
    const int j0   = (rem % TCOL) * 8;
    const int spx  = t & 31;
    const int cg   = t >> 5;
    const int pr   = spx >> 3, pc = spx & 7;
    const int i    = i0 + pr, j = j0 + pc;
    const int l15  = lane & 15;
    const int quad = lane >> 4;
    const int mtb  = wave >> 1;
    const int ntb  = wave & 1;

    const float* xb = xT + (size_t)(b * HW) * 64;

    // ============ PHASE 1: offset conv (dense taps, zero-pad mask) ============
    int okm = 0;
#pragma unroll
    for (int n = 0; n < 9; ++n) {
        int ii = i + n / 3 - 1, jj = j + n % 3 - 1;
        okm |= (int)((ii >= 0) & (ii < H) & (jj >= 0) & (jj < W)) << n;
    }

    f32x4 aoc = (f32x4){0.f, 0.f, 0.f, 0.f};

    for (int chunk = 0; chunk < 2; ++chunk) {
        // stage 8x12 patch (clamped borders; mask handles zero-pad)
#pragma unroll
        for (int k = 0; k < 3; ++k) {
            int idx = k * 256 + t;
            int slot = idx >> 3, e = idx & 7;
            int sr = slot / 12, sc = slot - sr * 12;
            int rr = min(max(i0 - 1 + sr, 0), H - 1);
            int cc = min(max(j0 - 1 + sc, 0), W - 1);
            float4 v = *(const float4*)(xb + (size_t)(rr * W + cc) * 64 + chunk * 32 + e * 4);
            *(float4*)&Xs[slot * SROW + e * 4] = v;
        }
        __syncthreads();
        short* wrh = &Ah[spx * AROW + cg * 4];
        short* wrl = &Al[spx * AROW + cg * 4];
#pragma unroll
        for (int n = 0; n < 9; ++n) {
            int slot = (pr + n / 3) * 12 + (pc + n % 3);
            float4 v = make_float4(0.f, 0.f, 0.f, 0.f);
            if ((okm >> n) & 1) v = *(float4*)&Xs[slot * SROW + cg * 4];
            s16x4 h4, l4;
            split_bf4(v.x, v.y, v.z, v.w, h4, l4);
            *(s16x4*)(wrh + n * 32) = h4;
            *(s16x4*)(wrl + n * 32) = l4;
        }
        __syncthreads();
        const short* aph = &Ah[(mtb * 16 + l15) * AROW + quad * 8];
        const short* apl = &Al[(mtb * 16 + l15) * AROW + quad * 8];
        const short* bph = Wtoh + (ntb * 16 + l15) * K576 + chunk * KCHUNK + quad * 8;
        const short* bpl = Wtol + (ntb * 16 + l15) * K576 + chunk * KCHUNK + quad * 8;
#pragma unroll
        for (int kt = 0; kt < 9; ++kt) {
            bf16x8 afh = *(const bf16x8*)(aph + kt * 32);
            bf16x8 afl = *(const bf16x8*)(apl + kt * 32);
            bf16x8 bfh = *(const bf16x8*)(bph + kt * 32);
            bf16x8 bfl = *(const bf16x8*)(bpl + kt * 32);
            aoc = __builtin_amdgcn_mfma_f32_16x16x32_bf16(afh, bfh, aoc, 0, 0, 0);
            aoc = __builtin_amdgcn_mfma_f32_16x16x32_bf16(afl, bfh, aoc, 0, 0, 0);
            aoc = __builtin_amdgcn_mfma_f32_16x16x32_bf16(afh, bfl, aoc, 0, 0, 0);
        }
        __syncthreads();
    }
    // offsets -> LDS (rows 18..31 of Wto are zero, so n=18,19 write 0+0)
    {
        int n = ntb * 16 + l15;
        if (n < OFFS) {
            float bi = (n < NOFF) ? boff[n] : 0.0f;
            int pxr = mtb * 16 + quad * 4;
#pragma unroll
            for (int r = 0; r < 4; ++r)
                offL[(pxr + r) * OFFS + n] = aoc[r] + bi;
        }
    }
    __syncthreads();

    // ============ PHASE 2: deformable sampling + conv ============
    float offa[20];
#pragma unroll
    for (int k = 0; k < 5; ++k)
        *(float4*)&offa[k * 4] = *(float4*)&offL[spx * OFFS + k * 4];

    float g0a[9], g1a[9], g2a[9], g3a[9];
    int   slp[9], cA[9], cB[9];
#pragma unroll
    for (int n = 0; n < 9; ++n) {
        float px_f = (float)(i + n / 3) + offa[n];
        float py_f = (float)(j + n % 3) + offa[9 + n];
        float qx = floorf(px_f), qy = floorf(py_f);
        int ltx = min(max((int)qx, 0), H - 1);
        int lty = min(max((int)qy, 0), W - 1);
        int rbx = min(max((int)qx + 1, 0), H - 1);
        int rby = min(max((int)qy + 1, 0), W - 1);
        float px = fminf(fmaxf(px_f, 0.0f), (float)(H - 1));
        float py = fminf(fmaxf(py_f, 0.0f), (float)(W - 1));
        float alt = 1.0f + ((float)ltx - px);
        float arb = 1.0f - ((float)rbx - px);
        float blt = 1.0f + ((float)lty - py);
        float brb = 1.0f - ((float)rby - py);
        g0a[n] = alt * blt; g1a[n] = arb * brb;
        g2a[n] = alt * brb; g3a[n] = arb * blt;
        int slr = ltx - (i0 - 1), srr = rbx - (i0 - 1);
        int slc = lty - (j0 - 1), src = rby - (j0 - 1);
        bool inp = ((unsigned)slr < 8u) & ((unsigned)srr < 8u) &
                   ((unsigned)slc < 12u) & ((unsigned)src < 12u);
        slp[n] = inp ? ((slr * 12 + slc) | ((srr * 12 + src) << 8) |
                        ((slr * 12 + src) << 16) | ((srr * 12 + slc) << 24)) : -1;
        cA[n] = (ltx << 16) | lty;
        cB[n] = (rbx << 16) | rby;
    }

    f32x4 acc[2];
    acc[0] = (f32x4){0.f, 0.f, 0.f, 0.f};
    acc[1] = (f32x4){0.f, 0.f, 0.f, 0.f};
    const int ntb0 = (wave & 1) * 2;

    for (int chunk = 0; chunk < 2; ++chunk) {
        const int ch = chunk * 32 + cg * 4;
#pragma unroll
        for (int k = 0; k < 3; ++k) {
            int idx = k * 256 + t;
            int slot = idx >> 3, e = idx & 7;
            int sr = slot / 12, sc = slot - sr * 12;
            int rr = min(max(i0 - 1 + sr, 0), H - 1);
            int cc = min(max(j0 - 1 + sc, 0), W - 1);
            float4 v = *(const float4*)(xb + (size_t)(rr * W + cc) * 64 + chunk * 32 + e * 4);
            *(float4*)&Xs[slot * SROW + e * 4] = v;
        }
        __syncthreads();
        short* wrh = &Ah[spx * AROW + cg * 4];
        short* wrl = &Al[spx * AROW + cg * 4];
#pragma unroll
        for (int n = 0; n < 9; ++n) {
            float4 v0, v1, v2, v3;
            int sp = slp[n];
            if (sp >= 0) {
                v0 = *(float4*)&Xs[(sp & 255) * SROW + cg * 4];
                v1 = *(float4*)&Xs[((sp >> 8) & 255) * SROW + cg * 4];
                v2 = *(float4*)&Xs[((sp >> 16) & 255) * SROW + cg * 4];
                v3 = *(float4*)&Xs[((sp >> 24) & 255) * SROW + cg * 4];
            } else {
                int ltx = cA[n] >> 16, lty = cA[n] & 0xffff;
                int rbx = cB[n] >> 16, rby = cB[n] & 0xffff;
                v0 = *(const float4*)(xb + (size_t)(ltx * W + lty) * 64 + ch);
                v1 = *(const float4*)(xb + (size_t)(rbx * W + rby) * 64 + ch);
                v2 = *(const float4*)(xb + (size_t)(ltx * W + rby) * 64 + ch);
                v3 = *(const float4*)(xb + (size_t)(rbx * W + lty) * 64 + ch);
            }
            float g0 = g0a[n], g1 = g1a[n], g2 = g2a[n], g3 = g3a[n];
            float s0 = g0 * v0.x + g1 * v1.x + g2 * v2.x + g3 * v3.x;
            float s1 = g0 * v0.y + g1 * v1.y + g2 * v2.y + g3 * v3.y;
            float s2 = g0 * v0.z + g1 * v1.z + g2 * v2.z + g3 * v3.z;
            float s3 = g0 * v0.w + g1 * v1.w + g2 * v2.w + g3 * v3.w;
            s16x4 h4, l4;
            split_bf4(s0, s1, s2, s3, h4, l4);
            *(s16x4*)(wrh + n * 32) = h4;
            *(s16x4*)(wrl + n * 32) = l4;
        }
        __syncthreads();
        const short* aph = &Ah[(mtb * 16 + l15) * AROW + quad * 8];
        const short* apl = &Al[(mtb * 16 + l15) * AROW + quad * 8];
        const short* bh0 = Wtdh + (ntb0 * 16 + l15) * K576 + chunk * KCHUNK + quad * 8;
        const short* bl0 = Wtdl + (ntb0 * 16 + l15) * K576 + chunk * KCHUNK + quad * 8;
#pragma unroll
        for (int kt = 0; kt < 9; ++kt) {
            bf16x8 afh = *(const bf16x8*)(aph + kt * 32);
            bf16x8 afl = *(const bf16x8*)(apl + kt * 32);
#pragma unroll
            for (int nt = 0; nt < 2; ++nt) {
                bf16x8 bfh = *(const bf16x8*)(bh0 + nt * 16 * K576 + kt * 32);
                bf16x8 bfl = *(const bf16x8*)(bl0 + nt * 16 * K576 + kt * 32);
                acc[nt] = __builtin_amdgcn_mfma_f32_16x16x32_bf16(afh, bfh, acc[nt], 0, 0, 0);
                acc[nt] = __builtin_amdgcn_mfma_f32_16x16x32_bf16(afl, bfh, acc[nt], 0, 0, 0);
                acc[nt] = __builtin_amdgcn_mfma_f32_16x16x32_bf16(afh, bfl, acc[nt], 0, 0, 0);
            }
        }
        __syncthreads();
    }

    // ============ EPILOGUE: store + fused stats ============
    float* Ld = (float*)smem;
    if (OUT_NHWC) {
        int pxr = mtb * 16 + quad * 4;
#pragma unroll
        for (int nt = 0; nt < 2; ++nt) {
            int c = (ntb0 + nt) * 16 + l15;
#pragma unroll
            for (int r = 0; r < 4; ++r)
                Ld[(pxr + r) * 72 + c] = acc[nt][r];
        }
        __syncthreads();
#pragma unroll
        for (int r = 0; r < 2; ++r) {
            int px = (t >> 4) + r * 16, c4 = t & 15;
            float4 v = *(float4*)&Ld[px * 72 + c4 * 4];
            int pij = (i0 + (px >> 3)) * W + j0 + (px & 7);
            *(float4*)(out + (size_t)(b * HW + pij) * 64 + c4 * 4) = v;
        }
    } else {
        int pxr = mtb * 16 + quad * 4;
#pragma unroll
        for (int nt = 0; nt < 2; ++nt) {
            int c = (ntb0 + nt) * 16 + l15;
#pragma unroll
            for (int r = 0; r < 4; ++r)
                Ld[c * 36 + pxr + r] = acc[nt][r];
        }
        __syncthreads();
#pragma unroll
        for (int cc = 0; cc < 2; ++cc) {
            int c = cc * 32 + (t >> 3), p4 = t & 7;
            float4 v = *(float4*)&Ld[c * 36 + p4 * 4];
            int px = p4 * 4;
            int pij = (i0 + (px >> 3)) * W + j0 + (px & 7);
            *(float4*)(out + (size_t)(b * COUT + c) * HW + pij) = v;
        }
    }
    // per-channel partials, contiguous 512 B per block
    {
        float* Sr = Xs;
        int c = t & 63, g = t >> 6;
        float s = 0.f, q = 0.f;
#pragma unroll
        for (int k = 0; k < 8; ++k) {
            int px = g * 8 + k;
            float v = OUT_NHWC ? Ld[px * 72 + c] : Ld[c * 36 + px];
            s += v; q += v * v;
        }
        Sr[g * 64 + c]       = s;
        Sr[256 + g * 64 + c] = q;
        __syncthreads();
        if (t < 64) {
            float ts = Sr[t] + Sr[64 + t] + Sr[128 + t] + Sr[192 + t];
            float tq = Sr[256 + t] + Sr[320 + t] + Sr[384 + t] + Sr[448 + t];
            part[(size_t)blockIdx.x * 128 + t]      = ts;
            part[(size_t)blockIdx.x * 128 + 64 + t] = tq;
        }
    }
}

// ---------------------------------------------------------------------------
// Reduce per-block partials -> per-channel scale/shift. grid = 64.
// ---------------------------------------------------------------------------
__global__ __launch_bounds__(256) void k_stats2(const float* __restrict__ part,
                                                const float* __restrict__ gamma,
                                                const float* __restrict__ beta,
                                                float* __restrict__ ss) {
    int c = blockIdx.x, t = threadIdx.x;
    float s = 0.f, q = 0.f;
    for (int k = t; k < NBLK; k += 256) {
        s += part[(size_t)k * 128 + c];
        q += part[(size_t)k * 128 + 64 + c];
    }
#pragma unroll
    for (int d = 32; d > 0; d >>= 1) {
        s += __shfl_down(s, d, 64);
        q += __shfl_down(q, d, 64);
    }
    __shared__ float red[8];
    int wv = t >> 6;
    if ((t & 63) == 0) { red[wv] = s; red[4 + wv] = q; }
    __syncthreads();
    if (t == 0) {
        float ts = red[0] + red[1] + red[2] + red[3];
        float tq = red[4] + red[5] + red[6] + red[7];
        const float inv_m = 1.0f / (float)(BATCH * HW);
        float mu    = ts * inv_m;
        float var   = tq * inv_m - mu * mu;
        float scale = rsqrtf(var + 1e-5f) * gamma[c];
        ss[c]      = scale;
        ss[64 + c] = beta[c] - mu * scale;
    }
}

// ---------------------------------------------------------------------------
// BN+ReLU on NHWC (stage 1).
// ---------------------------------------------------------------------------
__global__ __launch_bounds__(256) void k_bnrelu_nhwc(const float* __restrict__ y,
                                                     const float* __restrict__ ss,
                                                     float* __restrict__ out) {
    size_t idx = ((size_t)blockIdx.x * 256 + threadIdx.x) * 4;
    int c4 = (int)(idx & 63);
    float4 sc = *(const float4*)(ss + c4);
    float4 sh = *(const float4*)(ss + 64 + c4);
    float4 v  = *(const float4*)(y + idx);
    float4 r;
    r.x = fmaxf(fmaf(v.x, sc.x, sh.x), 0.f);
    r.y = fmaxf(fmaf(v.y, sc.y, sh.y), 0.f);
    r.z = fmaxf(fmaf(v.z, sc.z, sh.z), 0.f);
    r.w = fmaxf(fmaf(v.w, sc.w, sh.w), 0.f);
    *(float4*)(out + idx) = r;
}

// ---------------------------------------------------------------------------
// BN+ReLU on NCHW, IN-PLACE (stage 2).
// ---------------------------------------------------------------------------
__global__ __launch_bounds__(256) void k_bnrelu_nchw(float* __restrict__ y,
                                                     const float* __restrict__ ss) {
    int c = (blockIdx.x / 49) % COUT;
    float scale = ss[c], shift = ss[64 + c];
    size_t idx = ((size_t)blockIdx.x * 1024) + threadIdx.x * 4;
    float4 v = *(const float4*)(y + idx);
    float4 r;
    r.x = fmaxf(fmaf(v.x, scale, shift), 0.f);
    r.y = fmaxf(fmaf(v.y, scale, shift), 0.f);
    r.z = fmaxf(fmaf(v.z, scale, shift), 0.f);
    r.w = fmaxf(fmaf(v.w, scale, shift), 0.f);
    *(float4*)(y + idx) = r;
}

// ---------------------------------------------------------------------------
// Workspace (~28 MB): weights 216 KB | part 1.6 MB | ss 512 B |
// bufB(xT / y1 NHWC) 25.7 MB.  No off buffer (kept in LDS in k_fused).
// ---------------------------------------------------------------------------
extern "C" void kernel_launch(void* const* d_in, const int* in_sizes, int n_in,
                              void* d_out, int out_size, void* d_ws, size_t ws_size,
                              hipStream_t stream) {
    const float* x       = (const float*)d_in[0];
    const float* w_off1  = (const float*)d_in[1];
    const float* b_off1  = (const float*)d_in[2];
    const float* w_conv1 = (const float*)d_in[3];
    const float* gamma1  = (const float*)d_in[4];
    const float* beta1   = (const float*)d_in[5];
    const float* w_off2  = (const float*)d_in[6];
    const float* b_off2  = (const float*)d_in[7];
    const float* w_conv2 = (const float*)d_in[8];
    const float* gamma2  = (const float*)d_in[9];
    const float* beta2   = (const float*)d_in[10];
    float* out = (float*)d_out;

    char*  wsb  = (char*)d_ws;
    short* Wtdh = (short*)wsb;                           // 73728
    short* Wtdl = (short*)(wsb + 73728);                 // 73728
    short* Wtoh = (short*)(wsb + 147456);                // 36864
    short* Wtol = (short*)(wsb + 184320);                // 36864
    float* part = (float*)(wsb + 221184);                // 3136*128*4 = 1605632
    float* ss   = (float*)(wsb + 1826816);               // 512
    float* bufB = (float*)(wsb + 1827328);               // xT/y1: 25690112

    const int tp_blocks = (BATCH * HW) / 64;             // 1568
    const int bn_blocks = (BATCH * COUT * HW) / 1024;    // 6272

    // ---- stage 1 ----
    k_prepw       <<<216, 256, 0, stream>>>(w_conv1, w_off1, Wtdh, Wtdl, Wtoh, Wtol);
    k_transpose   <<<tp_blocks, 256, 0, stream>>>(x, bufB);
    k_fused<true> <<<NBLK, 256, 0, stream>>>(bufB, Wtoh, Wtol, b_off1, Wtdh, Wtdl, out, part);
    k_stats2      <<<64, 256, 0, stream>>>(part, gamma1, beta1, ss);
    k_bnrelu_nhwc <<<bn_blocks, 256, 0, stream>>>(out, ss, bufB);   // y1 (NHWC)

    // ---- stage 2 ----
    k_prepw       <<<216, 256, 0, stream>>>(w_conv2, w_off2, Wtdh, Wtdl, Wtoh, Wtol);
    k_fused<false><<<NBLK, 256, 0, stream>>>(bufB, Wtoh, Wtol, b_off2, Wtdh, Wtdl, out, part);
    k_stats2      <<<64, 256, 0, stream>>>(part, gamma2, beta2, ss);
    k_bnrelu_nchw <<<bn_blocks, 256, 0, stream>>>(out, ss);         // in-place
}

// Round 12
// 680.297 us; speedup vs baseline: 1.0146x; 1.0146x over previous
//
#include <hip/hip_runtime.h>

#define H 224
#define W 224
#define HW (H*W)
#define BATCH 2
#define CIN 64
#define COUT 64
#define NOFF 18
#define K576 576          // K = 64 ch * 9 taps
#define KCHUNK 288        // 32 ch * 9 taps per chunk (k = tap*32 + cc)
#define AROW 296          // 288 + 8 bf16 pad (592 B rows, 16B-aligned)
#define OFFS 20           // off LDS stride (18 live, f4-aligned)
#define NBLK (BATCH*HW/32)          // 3136 tiles (4x8 pixels)
#define NB8  (NBLK/8)               // 392 blocks per XCD span
#define TROW 56                     // row-tiles (224/4)
#define TCOL 28                     // col-tiles (224/8)
#define SROW 36                     // staged-patch stride in floats

typedef __attribute__((ext_vector_type(8))) short bf16x8;
typedef __attribute__((ext_vector_type(4))) short s16x4;
typedef __attribute__((ext_vector_type(4))) float f32x4;

__device__ inline short f2bf(float f) {
    unsigned u = __float_as_uint(f);
    u += 0x7FFF + ((u >> 16) & 1);
    return (short)(u >> 16);
}
__device__ inline float bf2f(short h) {
    return __uint_as_float(((unsigned)(unsigned short)h) << 16);
}
__device__ inline void split_bf(float x, short& hi, short& lo) {
    hi = f2bf(x);
    lo = f2bf(x - bf2f(hi));
}
__device__ inline void split_bf4(float a, float b, float c, float d,
                                 s16x4& h4, s16x4& l4) {
    short h0, l0, h1, l1, h2, l2, h3, l3;
    split_bf(a, h0, l0); split_bf(b, h1, l1);
    split_bf(c, h2, l2); split_bf(d, h3, l3);
    h4 = (s16x4){h0, h1, h2, h3};
    l4 = (s16x4){l0, l1, l2, l3};
}
__device__ inline int swizzle_blk(int raw) {
    return (raw & 7) * NB8 + (raw >> 3);
}
// Compile-time component select (idx is a literal after full unroll) —
// keeps offset values in VGPRs, NOT in an address-taken stack array
// (scratch spills were the 14x WRITE_SIZE amplification, R7-R11).
__device__ __forceinline__ float f4get(float4 v, int k) {
    switch (k & 3) { case 0: return v.x; case 1: return v.y; case 2: return v.z; default: return v.w; }
}

// ---------------------------------------------------------------------------
// Weight prep: split into hi/lo bf16, permute K to chunk*288 + tap*32 + cc.
// ---------------------------------------------------------------------------
__global__ __launch_bounds__(256) void k_prepw(const float* __restrict__ wconv,
                                               const float* __restrict__ woff,
                                               short* __restrict__ Wtdh,
                                               short* __restrict__ Wtdl,
                                               short* __restrict__ Wtoh,
                                               short* __restrict__ Wtol) {
    int t = blockIdx.x * 256 + threadIdx.x;
    if (t < COUT * K576) {
        int n = t / K576, kp = t - n * K576;
        int chunk = kp / KCHUNK, r = kp - chunk * KCHUNK;
        int tap = r >> 5, cc = r & 31;
        int c = chunk * 32 + cc;
        short h, l; split_bf(wconv[n * K576 + c * 9 + tap], h, l);
        Wtdh[t] = h; Wtdl[t] = l;
    }
    int t2 = t - COUT * K576;
    if (t2 >= 0 && t2 < 32 * K576) {
        int n = t2 / K576, kp = t2 - n * K576;
        int chunk = kp / KCHUNK, r = kp - chunk * KCHUNK;
        int tap = r >> 5, cc = r & 31;
        int c = chunk * 32 + cc;
        float v = (n < NOFF) ? woff[n * K576 + c * 9 + tap] : 0.0f;
        short h, l; split_bf(v, h, l);
        Wtoh[t2] = h; Wtol[t2] = l;
    }
}

// ---------------------------------------------------------------------------
// x NCHW -> NHWC.
// ---------------------------------------------------------------------------
__global__ __launch_bounds__(256) void k_transpose(const float* __restrict__ x,
                                                   float* __restrict__ xT) {
    __shared__ float Lt[64][65];
    int blk = blockIdx.x, t = threadIdx.x;
    int px0 = blk * 64;
    int b   = px0 / HW;
    int ij0 = px0 - b * HW;
    int lane = t & 63, g = t >> 6;
#pragma unroll
    for (int r = 0; r < 16; ++r) {
        int c = r * 4 + g;
        Lt[c][lane] = x[(b * CIN + c) * HW + ij0 + lane];
    }
    __syncthreads();
#pragma unroll
    for (int r = 0; r < 16; ++r) {
        int px = r * 4 + g;
        xT[((size_t)(b * HW + ij0 + px)) * 64 + lane] = Lt[lane][px];
    }
}

// ---------------------------------------------------------------------------
// FUSED per 4x8 tile: offset-conv GEMM -> offsets in LDS -> deformable
// sampling (LDS patch, global fallback) -> deform GEMM -> stores + fused
// stats. Phase 2 uses ZERO per-thread arrays (scratch-free): offsets live in
// five named float4 regs; bilinear setup recomputed per chunk with scalars.
// ---------------------------------------------------------------------------
template <bool OUT_NHWC>
__global__ __launch_bounds__(256, 3) void k_fused(const float* __restrict__ xT,
                                                  const short* __restrict__ Wtoh,
                                                  const short* __restrict__ Wtol,
                                                  const float* __restrict__ boff,
                                                  const short* __restrict__ Wtdh,
                                                  const short* __restrict__ Wtdl,
                                                  float* __restrict__ out,
                                                  float* __restrict__ part) {
    // LDS: Ah/Al 37888 | Xs 13824 | offL 2560  = 54272 B (x3 <= 160 KiB)
    __shared__ __align__(16) char smem[2 * 32 * AROW * 2 + 96 * SROW * 4 + 32 * OFFS * 4];
    short* Ah   = (short*)smem;
    short* Al   = Ah + 32 * AROW;
    float* Xs   = (float*)(smem + 2 * 32 * AROW * 2);
    float* offL = (float*)(smem + 2 * 32 * AROW * 2 + 96 * SROW * 4);

    const int t    = threadIdx.x;
    const int lane = t & 63;
    const int wave = t >> 6;
    const int vb   = swizzle_blk(blockIdx.x);
    const int b    = vb / (TROW * TCOL);
    const int rem  = vb - b * (TROW * TCOL);
    const int i0   = (rem / TCOL) * 4;
    const int j0   = (rem % TCOL) * 8;
    const int spx  = t & 31;
    const int cg   = t >> 5;
    const int pr   = spx >> 3, pc = spx & 7;
    const int i    = i0 + pr, j = j0 + pc;
    const int l15  = lane & 15;
    const int quad = lane >> 4;
    const int mtb  = wave >> 1;
    const int ntb  = wave & 1;

    const float* xb = xT + (size_t)(b * HW) * 64;

    // ============ PHASE 1: offset conv (dense taps, zero-pad mask) ============
    int okm = 0;
#pragma unroll
    for (int n = 0; n < 9; ++n) {
        int ii = i + n / 3 - 1, jj = j + n % 3 - 1;
        okm |= (int)((ii >= 0) & (ii < H) & (jj >= 0) & (jj < W)) << n;
    }

    f32x4 aoc = (f32x4){0.f, 0.f, 0.f, 0.f};

    for (int chunk = 0; chunk < 2; ++chunk) {
#pragma unroll
        for (int k = 0; k < 3; ++k) {
            int idx = k * 256 + t;
            int slot = idx >> 3, e = idx & 7;
            int sr = slot / 12, sc = slot - sr * 12;
            int rr = min(max(i0 - 1 + sr, 0), H - 1);
            int cc = min(max(j0 - 1 + sc, 0), W - 1);
            float4 v = *(const float4*)(xb + (size_t)(rr * W + cc) * 64 + chunk * 32 + e * 4);
            *(float4*)&Xs[slot * SROW + e * 4] = v;
        }
        __syncthreads();
        short* wrh = &Ah[spx * AROW + cg * 4];
        short* wrl = &Al[spx * AROW + cg * 4];
#pragma unroll
        for (int n = 0; n < 9; ++n) {
            int slot = (pr + n / 3) * 12 + (pc + n % 3);
            float4 v = make_float4(0.f, 0.f, 0.f, 0.f);
            if ((okm >> n) & 1) v = *(float4*)&Xs[slot * SROW + cg * 4];
            s16x4 h4, l4;
            split_bf4(v.x, v.y, v.z, v.w, h4, l4);
            *(s16x4*)(wrh + n * 32) = h4;
            *(s16x4*)(wrl + n * 32) = l4;
        }
        __syncthreads();
        const short* aph = &Ah[(mtb * 16 + l15) * AROW + quad * 8];
        const short* apl = &Al[(mtb * 16 + l15) * AROW + quad * 8];
        const short* bph = Wtoh + (ntb * 16 + l15) * K576 + chunk * KCHUNK + quad * 8;
        const short* bpl = Wtol + (ntb * 16 + l15) * K576 + chunk * KCHUNK + quad * 8;
#pragma unroll
        for (int kt = 0; kt < 9; ++kt) {
            bf16x8 afh = *(const bf16x8*)(aph + kt * 32);
            bf16x8 afl = *(const bf16x8*)(apl + kt * 32);
            bf16x8 bfh = *(const bf16x8*)(bph + kt * 32);
            bf16x8 bfl = *(const bf16x8*)(bpl + kt * 32);
            aoc = __builtin_amdgcn_mfma_f32_16x16x32_bf16(afh, bfh, aoc, 0, 0, 0);
            aoc = __builtin_amdgcn_mfma_f32_16x16x32_bf16(afl, bfh, aoc, 0, 0, 0);
            aoc = __builtin_amdgcn_mfma_f32_16x16x32_bf16(afh, bfl, aoc, 0, 0, 0);
        }
        __syncthreads();
    }
    {
        int n = ntb * 16 + l15;
        if (n < OFFS) {
            float bi = (n < NOFF) ? boff[n] : 0.0f;
            int pxr = mtb * 16 + quad * 4;
#pragma unroll
            for (int r = 0; r < 4; ++r)
                offL[(pxr + r) * OFFS + n] = aoc[r] + bi;
        }
    }
    __syncthreads();

    // ============ PHASE 2: deformable sampling + conv (scratch-free) ============
    // offsets in five NAMED float4 registers (no address-taken array)
    const float4 ofA = *(float4*)&offL[spx * OFFS + 0];
    const float4 ofB = *(float4*)&offL[spx * OFFS + 4];
    const float4 ofC = *(float4*)&offL[spx * OFFS + 8];
    const float4 ofD = *(float4*)&offL[spx * OFFS + 12];
    const float4 ofE = *(float4*)&offL[spx * OFFS + 16];
#define OFFSEL(idx) ((idx) < 4 ? f4get(ofA, (idx)) : (idx) < 8 ? f4get(ofB, (idx)-4) : \
                     (idx) < 12 ? f4get(ofC, (idx)-8) : (idx) < 16 ? f4get(ofD, (idx)-12) : f4get(ofE, (idx)-16))

    f32x4 acc[2];
    acc[0] = (f32x4){0.f, 0.f, 0.f, 0.f};
    acc[1] = (f32x4){0.f, 0.f, 0.f, 0.f};
    const int ntb0 = (wave & 1) * 2;

    for (int chunk = 0; chunk < 2; ++chunk) {
        const int ch = chunk * 32 + cg * 4;
#pragma unroll
        for (int k = 0; k < 3; ++k) {
            int idx = k * 256 + t;
            int slot = idx >> 3, e = idx & 7;
            int sr = slot / 12, sc = slot - sr * 12;
            int rr = min(max(i0 - 1 + sr, 0), H - 1);
            int cc = min(max(j0 - 1 + sc, 0), W - 1);
            float4 v = *(const float4*)(xb + (size_t)(rr * W + cc) * 64 + chunk * 32 + e * 4);
            *(float4*)&Xs[slot * SROW + e * 4] = v;
        }
        __syncthreads();
        short* wrh = &Ah[spx * AROW + cg * 4];
        short* wrl = &Al[spx * AROW + cg * 4];
#pragma unroll
        for (int n = 0; n < 9; ++n) {
            float px_f = (float)(i + n / 3) + OFFSEL(n);
            float py_f = (float)(j + n % 3) + OFFSEL(9 + n);
            float qx = floorf(px_f), qy = floorf(py_f);
            int ltx = min(max((int)qx, 0), H - 1);
            int lty = min(max((int)qy, 0), W - 1);
            int rbx = min(max((int)qx + 1, 0), H - 1);
            int rby = min(max((int)qy + 1, 0), W - 1);
            float px = fminf(fmaxf(px_f, 0.0f), (float)(H - 1));
            float py = fminf(fmaxf(py_f, 0.0f), (float)(W - 1));
            float alt = 1.0f + ((float)ltx - px);
            float arb = 1.0f - ((float)rbx - px);
            float blt = 1.0f + ((float)lty - py);
            float brb = 1.0f - ((float)rby - py);
            float g0 = alt * blt, g1 = arb * brb, g2 = alt * brb, g3 = arb * blt;
            int slr = ltx - (i0 - 1), srr = rbx - (i0 - 1);
            int slc = lty - (j0 - 1), src = rby - (j0 - 1);
            float4 v0, v1, v2, v3;
            if (((unsigned)slr < 8u) & ((unsigned)srr < 8u) &
                ((unsigned)slc < 12u) & ((unsigned)src < 12u)) {
                v0 = *(float4*)&Xs[(slr * 12 + slc) * SROW + cg * 4];
                v1 = *(float4*)&Xs[(srr * 12 + src) * SROW + cg * 4];
                v2 = *(float4*)&Xs[(slr * 12 + src) * SROW + cg * 4];
                v3 = *(float4*)&Xs[(srr * 12 + slc) * SROW + cg * 4];
            } else {
                v0 = *(const float4*)(xb + (size_t)(ltx * W + lty) * 64 + ch);
                v1 = *(const float4*)(xb + (size_t)(rbx * W + rby) * 64 + ch);
                v2 = *(const float4*)(xb + (size_t)(ltx * W + rby) * 64 + ch);
                v3 = *(const float4*)(xb + (size_t)(rbx * W + lty) * 64 + ch);
            }
            float s0 = g0 * v0.x + g1 * v1.x + g2 * v2.x + g3 * v3.x;
            float s1 = g0 * v0.y + g1 * v1.y + g2 * v2.y + g3 * v3.y;
            float s2 = g0 * v0.z + g1 * v1.z + g2 * v2.z + g3 * v3.z;
            float s3 = g0 * v0.w + g1 * v1.w + g2 * v2.w + g3 * v3.w;
            s16x4 h4, l4;
            split_bf4(s0, s1, s2, s3, h4, l4);
            *(s16x4*)(wrh + n * 32) = h4;
            *(s16x4*)(wrl + n * 32) = l4;
        }
        __syncthreads();
        const short* aph = &Ah[(mtb * 16 + l15) * AROW + quad * 8];
        const short* apl = &Al[(mtb * 16 + l15) * AROW + quad * 8];
        const short* bh0 = Wtdh + (ntb0 * 16 + l15) * K576 + chunk * KCHUNK + quad * 8;
        const short* bl0 = Wtdl + (ntb0 * 16 + l15) * K576 + chunk * KCHUNK + quad * 8;
#pragma unroll
        for (int kt = 0; kt < 9; ++kt) {
            bf16x8 afh = *(const bf16x8*)(aph + kt * 32);
            bf16x8 afl = *(const bf16x8*)(apl + kt * 32);
#pragma unroll
            for (int nt = 0; nt < 2; ++nt) {
                bf16x8 bfh = *(const bf16x8*)(bh0 + nt * 16 * K576 + kt * 32);
                bf16x8 bfl = *(const bf16x8*)(bl0 + nt * 16 * K576 + kt * 32);
                acc[nt] = __builtin_amdgcn_mfma_f32_16x16x32_bf16(afh, bfh, acc[nt], 0, 0, 0);
                acc[nt] = __builtin_amdgcn_mfma_f32_16x16x32_bf16(afl, bfh, acc[nt], 0, 0, 0);
                acc[nt] = __builtin_amdgcn_mfma_f32_16x16x32_bf16(afh, bfl, acc[nt], 0, 0, 0);
            }
        }
        __syncthreads();
    }
#undef OFFSEL

    // ============ EPILOGUE: store + fused stats ============
    float* Ld = (float*)smem;
    if (OUT_NHWC) {
        int pxr = mtb * 16 + quad * 4;
#pragma unroll
        for (int nt = 0; nt < 2; ++nt) {
            int c = (ntb0 + nt) * 16 + l15;
#pragma unroll
            for (int r = 0; r < 4; ++r)
                Ld[(pxr + r) * 72 + c] = acc[nt][r];
        }
        __syncthreads();
#pragma unroll
        for (int r = 0; r < 2; ++r) {
            int px = (t >> 4) + r * 16, c4 = t & 15;
            float4 v = *(float4*)&Ld[px * 72 + c4 * 4];
            int pij = (i0 + (px >> 3)) * W + j0 + (px & 7);
            *(float4*)(out + (size_t)(b * HW + pij) * 64 + c4 * 4) = v;
        }
    } else {
        int pxr = mtb * 16 + quad * 4;
#pragma unroll
        for (int nt = 0; nt < 2; ++nt) {
            int c = (ntb0 + nt) * 16 + l15;
#pragma unroll
            for (int r = 0; r < 4; ++r)
                Ld[c * 36 + pxr + r] = acc[nt][r];
        }
        __syncthreads();
#pragma unroll
        for (int cc = 0; cc < 2; ++cc) {
            int c = cc * 32 + (t >> 3), p4 = t & 7;
            float4 v = *(float4*)&Ld[c * 36 + p4 * 4];
            int px = p4 * 4;
            int pij = (i0 + (px >> 3)) * W + j0 + (px & 7);
            *(float4*)(out + (size_t)(b * COUT + c) * HW + pij) = v;
        }
    }
    {
        float* Sr = Xs;
        int c = t & 63, g = t >> 6;
        float s = 0.f, q = 0.f;
#pragma unroll
        for (int k = 0; k < 8; ++k) {
            int px = g * 8 + k;
            float v = OUT_NHWC ? Ld[px * 72 + c] : Ld[c * 36 + px];
            s += v; q += v * v;
        }
        Sr[g * 64 + c]       = s;
        Sr[256 + g * 64 + c] = q;
        __syncthreads();
        if (t < 64) {
            float ts = Sr[t] + Sr[64 + t] + Sr[128 + t] + Sr[192 + t];
            float tq = Sr[256 + t] + Sr[320 + t] + Sr[384 + t] + Sr[448 + t];
            part[(size_t)blockIdx.x * 128 + t]      = ts;
            part[(size_t)blockIdx.x * 128 + 64 + t] = tq;
        }
    }
}

// ---------------------------------------------------------------------------
// Reduce per-block partials -> per-channel scale/shift. grid = 64.
// ---------------------------------------------------------------------------
__global__ __launch_bounds__(256) void k_stats2(const float* __restrict__ part,
                                                const float* __restrict__ gamma,
                                                const float* __restrict__ beta,
                                                float* __restrict__ ss) {
    int c = blockIdx.x, t = threadIdx.x;
    float s = 0.f, q = 0.f;
    for (int k = t; k < NBLK; k += 256) {
        s += part[(size_t)k * 128 + c];
        q += part[(size_t)k * 128 + 64 + c];
    }
#pragma unroll
    for (int d = 32; d > 0; d >>= 1) {
        s += __shfl_down(s, d, 64);
        q += __shfl_down(q, d, 64);
    }
    __shared__ float red[8];
    int wv = t >> 6;
    if ((t & 63) == 0) { red[wv] = s; red[4 + wv] = q; }
    __syncthreads();
    if (t == 0) {
        float ts = red[0] + red[1] + red[2] + red[3];
        float tq = red[4] + red[5] + red[6] + red[7];
        const float inv_m = 1.0f / (float)(BATCH * HW);
        float mu    = ts * inv_m;
        float var   = tq * inv_m - mu * mu;
        float scale = rsqrtf(var + 1e-5f) * gamma[c];
        ss[c]      = scale;
        ss[64 + c] = beta[c] - mu * scale;
    }
}

// ---------------------------------------------------------------------------
// BN+ReLU on NHWC (stage 1).
// ---------------------------------------------------------------------------
__global__ __launch_bounds__(256) void k_bnrelu_nhwc(const float* __restrict__ y,
                                                     const float* __restrict__ ss,
                                                     float* __restrict__ out) {
    size_t idx = ((size_t)blockIdx.x * 256 + threadIdx.x) * 4;
    int c4 = (int)(idx & 63);
    float4 sc = *(const float4*)(ss + c4);
    float4 sh = *(const float4*)(ss + 64 + c4);
    float4 v  = *(const float4*)(y + idx);
    float4 r;
    r.x = fmaxf(fmaf(v.x, sc.x, sh.x), 0.f);
    r.y = fmaxf(fmaf(v.y, sc.y, sh.y), 0.f);
    r.z = fmaxf(fmaf(v.z, sc.z, sh.z), 0.f);
    r.w = fmaxf(fmaf(v.w, sc.w, sh.w), 0.f);
    *(float4*)(out + idx) = r;
}

// ---------------------------------------------------------------------------
// BN+ReLU on NCHW, IN-PLACE (stage 2).
// ---------------------------------------------------------------------------
__global__ __launch_bounds__(256) void k_bnrelu_nchw(float* __restrict__ y,
                                                     const float* __restrict__ ss) {
    int c = (blockIdx.x / 49) % COUT;
    float scale = ss[c], shift = ss[64 + c];
    size_t idx = ((size_t)blockIdx.x * 1024) + threadIdx.x * 4;
    float4 v = *(const float4*)(y + idx);
    float4 r;
    r.x = fmaxf(fmaf(v.x, scale, shift), 0.f);
    r.y = fmaxf(fmaf(v.y, scale, shift), 0.f);
    r.z = fmaxf(fmaf(v.z, scale, shift), 0.f);
    r.w = fmaxf(fmaf(v.w, scale, shift), 0.f);
    *(float4*)(y + idx) = r;
}

// ---------------------------------------------------------------------------
// Workspace (~28 MB): weights 216 KB | part 1.6 MB | ss 512 B |
// bufB(xT / y1 NHWC) 25.7 MB.
// ---------------------------------------------------------------------------
extern "C" void kernel_launch(void* const* d_in, const int* in_sizes, int n_in,
                              void* d_out, int out_size, void* d_ws, size_t ws_size,
                              hipStream_t stream) {
    const float* x       = (const float*)d_in[0];
    const float* w_off1  = (const float*)d_in[1];
    const float* b_off1  = (const float*)d_in[2];
    const float* w_conv1 = (const float*)d_in[3];
    const float* gamma1  = (const float*)d_in[4];
    const float* beta1   = (const float*)d_in[5];
    const float* w_off2  = (const float*)d_in[6];
    const float* b_off2  = (const float*)d_in[7];
    const float* w_conv2 = (const float*)d_in[8];
    const float* gamma2  = (const float*)d_in[9];
    const float* beta2   = (const float*)d_in[10];
    float* out = (float*)d_out;

    char*  wsb  = (char*)d_ws;
    short* Wtdh = (short*)wsb;                           // 73728
    short* Wtdl = (short*)(wsb + 73728);                 // 73728
    short* Wtoh = (short*)(wsb + 147456);                // 36864
    short* Wtol = (short*)(wsb + 184320);                // 36864
    float* part = (float*)(wsb + 221184);                // 3136*128*4 = 1605632
    float* ss   = (float*)(wsb + 1826816);               // 512
    float* bufB = (float*)(wsb + 1827328);               // xT/y1: 25690112

    const int tp_blocks = (BATCH * HW) / 64;             // 1568
    const int bn_blocks = (BATCH * COUT * HW) / 1024;    // 6272

    // ---- stage 1 ----
    k_prepw       <<<216, 256, 0, stream>>>(w_conv1, w_off1, Wtdh, Wtdl, Wtoh, Wtol);
    k_transpose   <<<tp_blocks, 256, 0, stream>>>(x, bufB);
    k_fused<true> <<<NBLK, 256, 0, stream>>>(bufB, Wtoh, Wtol, b_off1, Wtdh, Wtdl, out, part);
    k_stats2      <<<64, 256, 0, stream>>>(part, gamma1, beta1, ss);
    k_bnrelu_nhwc <<<bn_blocks, 256, 0, stream>>>(out, ss, bufB);   // y1 (NHWC)

    // ---- stage 2 ----
    k_prepw       <<<216, 256, 0, stream>>>(w_conv2, w_off2, Wtdh, Wtdl, Wtoh, Wtol);
    k_fused<false><<<NBLK, 256, 0, stream>>>(bufB, Wtoh, Wtol, b_off2, Wtdh, Wtdl, out, part);
    k_stats2      <<<64, 256, 0, stream>>>(part, gamma2, beta2, ss);
    k_bnrelu_nchw <<<bn_blocks, 256, 0, stream>>>(out, ss);         // in-place
}

// Round 13
// 341.806 us; speedup vs baseline: 2.0194x; 1.9903x over previous
//
#include <hip/hip_runtime.h>

#define H 224
#define W 224
#define HW (H*W)
#define BATCH 2
#define CIN 64
#define COUT 64
#define NOFF 18
#define K576 576          // K = 64 ch * 9 taps
#define KCHUNK 288        // 32 ch * 9 taps per chunk
#define AROW 296          // 288 + 8 bf16 pad
#define OFFS 20           // off LDS stride (18 live, f4-aligned)
#define NBLK (BATCH*HW/32)          // 3136 tiles (4x8 pixels)
#define NB8  (NBLK/8)               // 392 blocks per XCD span
#define TROW 56
#define TCOL 28
#define XROW 68                     // full-ch staged patch stride (64 + 4 pad)

typedef __attribute__((ext_vector_type(8))) short bf16x8;
typedef __attribute__((ext_vector_type(4))) short s16x4;
typedef __attribute__((ext_vector_type(4))) float f32x4;

__device__ inline short f2bf(float f) {
    unsigned u = __float_as_uint(f);
    u += 0x7FFF + ((u >> 16) & 1);
    return (short)(u >> 16);
}
__device__ inline float bf2f(short h) {
    return __uint_as_float(((unsigned)(unsigned short)h) << 16);
}
__device__ inline void split_bf(float x, short& hi, short& lo) {
    hi = f2bf(x);
    lo = f2bf(x - bf2f(hi));
}
__device__ inline void split_bf4(float a, float b, float c, float d,
                                 s16x4& h4, s16x4& l4) {
    short h0, l0, h1, l1, h2, l2, h3, l3;
    split_bf(a, h0, l0); split_bf(b, h1, l1);
    split_bf(c, h2, l2); split_bf(d, h3, l3);
    h4 = (s16x4){h0, h1, h2, h3};
    l4 = (s16x4){l0, l1, l2, l3};
}
__device__ inline int swizzle_blk(int raw) {
    return (raw & 7) * NB8 + (raw >> 3);
}
__device__ __forceinline__ float f4get(float4 v, int k) {
    switch (k & 3) { case 0: return v.x; case 1: return v.y; case 2: return v.z; default: return v.w; }
}

// ---------------------------------------------------------------------------
// Weight prep -> WAVE-CONTIGUOUS fragment layout: each wave's B-fragment load
// is one contiguous 1 KB block (was: 64 scattered 16-B chunks / 64 lines).
// Deform:  Wd[((chunk*9+kt)*4+nt)*512 + lane*8 + e]
//   n = nt*16 + (lane&15); c = chunk*32 + (lane>>4)*8 + e; tap = kt
// Offconv: Wo[((chunk*9+kt)*2+ntb)*512 + lane*8 + e]   (n>=18 rows zero)
// ---------------------------------------------------------------------------
__global__ __launch_bounds__(256) void k_prepw(const float* __restrict__ wconv,
                                               const float* __restrict__ woff,
                                               short* __restrict__ Wtdh,
                                               short* __restrict__ Wtdl,
                                               short* __restrict__ Wtoh,
                                               short* __restrict__ Wtol) {
    int t = blockIdx.x * 256 + threadIdx.x;
    if (t < COUT * K576) {
        int e = t & 7, lane = (t >> 3) & 63, rest = t >> 9;
        int nt = rest & 3, kt9 = rest >> 2;
        int kt = kt9 % 9, chunk = kt9 / 9;
        int n = nt * 16 + (lane & 15);
        int c = chunk * 32 + (lane >> 4) * 8 + e;
        short h, l; split_bf(wconv[n * K576 + c * 9 + kt], h, l);
        Wtdh[t] = h; Wtdl[t] = l;
    }
    int t2 = t - COUT * K576;
    if (t2 >= 0 && t2 < 32 * K576) {
        int e = t2 & 7, lane = (t2 >> 3) & 63, rest = t2 >> 9;
        int ntb = rest & 1, kt9 = rest >> 1;
        int kt = kt9 % 9, chunk = kt9 / 9;
        int n = ntb * 16 + (lane & 15);
        int c = chunk * 32 + (lane >> 4) * 8 + e;
        float v = (n < NOFF) ? woff[n * K576 + c * 9 + kt] : 0.0f;
        short h, l; split_bf(v, h, l);
        Wtoh[t2] = h; Wtol[t2] = l;
    }
}

// ---------------------------------------------------------------------------
// x NCHW -> NHWC.
// ---------------------------------------------------------------------------
__global__ __launch_bounds__(256) void k_transpose(const float* __restrict__ x,
                                                   float* __restrict__ xT) {
    __shared__ float Lt[64][65];
    int blk = blockIdx.x, t = threadIdx.x;
    int px0 = blk * 64;
    int b   = px0 / HW;
    int ij0 = px0 - b * HW;
    int lane = t & 63, g = t >> 6;
#pragma unroll
    for (int r = 0; r < 16; ++r) {
        int c = r * 4 + g;
        Lt[c][lane] = x[(b * CIN + c) * HW + ij0 + lane];
    }
    __syncthreads();
#pragma unroll
    for (int r = 0; r < 16; ++r) {
        int px = r * 4 + g;
        xT[((size_t)(b * HW + ij0 + px)) * 64 + lane] = Lt[lane][px];
    }
}

// ---------------------------------------------------------------------------
// FUSED per 4x8 tile. The 8x12x64ch x-patch is staged ONCE (26.1 KB, stride
// 68 floats) and shared by offset-conv phase AND deform phase, both chunks
// (was 4 identical stagings). Weights read via wave-contiguous fragments.
// LDS 66560 B -> 2 blocks/CU.
// ---------------------------------------------------------------------------
template <bool OUT_NHWC>
__global__ __launch_bounds__(256, 2) void k_fused(const float* __restrict__ xT,
                                                  const short* __restrict__ Wtoh,
                                                  const short* __restrict__ Wtol,
                                                  const float* __restrict__ boff,
                                                  const short* __restrict__ Wtdh,
                                                  const short* __restrict__ Wtdl,
                                                  float* __restrict__ out,
                                                  float* __restrict__ part) {
    // LDS: Ah/Al 37888 | Xs 26112 | offL 2560 = 66560 B
    __shared__ __align__(16) char smem[2 * 32 * AROW * 2 + 96 * XROW * 4 + 32 * OFFS * 4];
    short* Ah   = (short*)smem;
    short* Al   = Ah + 32 * AROW;
    float* Xs   = (float*)(smem + 2 * 32 * AROW * 2);
    float* offL = (float*)(smem + 2 * 32 * AROW * 2 + 96 * XROW * 4);

    const int t    = threadIdx.x;
    const int lane = t & 63;
    const int wave = t >> 6;
    const int vb   = swizzle_blk(blockIdx.x);
    const int b    = vb / (TROW * TCOL);
    const int rem  = vb - b * (TROW * TCOL);
    const int i0   = (rem / TCOL) * 4;
    const int j0   = (rem % TCOL) * 8;
    const int spx  = t & 31;
    const int cg   = t >> 5;
    const int pr   = spx >> 3, pc = spx & 7;
    const int i    = i0 + pr, j = j0 + pc;
    const int l15  = lane & 15;
    const int quad = lane >> 4;
    const int mtb  = wave >> 1;
    const int ntb  = wave & 1;

    const float* xb = xT + (size_t)(b * HW) * 64;

    // ---- stage full 8x12x64ch patch ONCE (border-clamped) ----
#pragma unroll
    for (int k = 0; k < 6; ++k) {
        int idx = k * 256 + t;               // 1536 = 96 slots x 16 f4
        int slot = idx >> 4, e = idx & 15;
        int sr = slot / 12, sc = slot - sr * 12;
        int rr = min(max(i0 - 1 + sr, 0), H - 1);
        int cc = min(max(j0 - 1 + sc, 0), W - 1);
        float4 v = *(const float4*)(xb + (size_t)(rr * W + cc) * 64 + e * 4);
        *(float4*)&Xs[slot * XROW + e * 4] = v;
    }
    __syncthreads();

    // ============ PHASE 1: offset conv (zero-pad via mask) ============
    int okm = 0;
#pragma unroll
    for (int n = 0; n < 9; ++n) {
        int ii = i + n / 3 - 1, jj = j + n % 3 - 1;
        okm |= (int)((ii >= 0) & (ii < H) & (jj >= 0) & (jj < W)) << n;
    }

    f32x4 aoc = (f32x4){0.f, 0.f, 0.f, 0.f};

    for (int chunk = 0; chunk < 2; ++chunk) {
        short* wrh = &Ah[spx * AROW + cg * 4];
        short* wrl = &Al[spx * AROW + cg * 4];
#pragma unroll
        for (int n = 0; n < 9; ++n) {
            int slot = (pr + n / 3) * 12 + (pc + n % 3);
            float4 v = make_float4(0.f, 0.f, 0.f, 0.f);
            if ((okm >> n) & 1) v = *(float4*)&Xs[slot * XROW + chunk * 32 + cg * 4];
            s16x4 h4, l4;
            split_bf4(v.x, v.y, v.z, v.w, h4, l4);
            *(s16x4*)(wrh + n * 32) = h4;
            *(s16x4*)(wrl + n * 32) = l4;
        }
        __syncthreads();
        const short* aph = &Ah[(mtb * 16 + l15) * AROW + quad * 8];
        const short* apl = &Al[(mtb * 16 + l15) * AROW + quad * 8];
#pragma unroll
        for (int kt = 0; kt < 9; ++kt) {
            bf16x8 afh = *(const bf16x8*)(aph + kt * 32);
            bf16x8 afl = *(const bf16x8*)(apl + kt * 32);
            int fb = ((chunk * 9 + kt) * 2 + ntb) * 512 + lane * 8;
            bf16x8 bfh = *(const bf16x8*)(Wtoh + fb);
            bf16x8 bfl = *(const bf16x8*)(Wtol + fb);
            aoc = __builtin_amdgcn_mfma_f32_16x16x32_bf16(afh, bfh, aoc, 0, 0, 0);
            aoc = __builtin_amdgcn_mfma_f32_16x16x32_bf16(afl, bfh, aoc, 0, 0, 0);
            aoc = __builtin_amdgcn_mfma_f32_16x16x32_bf16(afh, bfl, aoc, 0, 0, 0);
        }
        __syncthreads();
    }
    {
        int n = ntb * 16 + l15;
        if (n < OFFS) {
            float bi = (n < NOFF) ? boff[n] : 0.0f;
            int pxr = mtb * 16 + quad * 4;
#pragma unroll
            for (int r = 0; r < 4; ++r)
                offL[(pxr + r) * OFFS + n] = aoc[r] + bi;
        }
    }
    __syncthreads();

    // ============ PHASE 2: deformable sampling + conv ============
    const float4 ofA = *(float4*)&offL[spx * OFFS + 0];
    const float4 ofB = *(float4*)&offL[spx * OFFS + 4];
    const float4 ofC = *(float4*)&offL[spx * OFFS + 8];
    const float4 ofD = *(float4*)&offL[spx * OFFS + 12];
    const float4 ofE = *(float4*)&offL[spx * OFFS + 16];
#define OFFSEL(idx) ((idx) < 4 ? f4get(ofA, (idx)) : (idx) < 8 ? f4get(ofB, (idx)-4) : \
                     (idx) < 12 ? f4get(ofC, (idx)-8) : (idx) < 16 ? f4get(ofD, (idx)-12) : f4get(ofE, (idx)-16))

    f32x4 acc[2];
    acc[0] = (f32x4){0.f, 0.f, 0.f, 0.f};
    acc[1] = (f32x4){0.f, 0.f, 0.f, 0.f};
    const int ntb0 = (wave & 1) * 2;

    for (int chunk = 0; chunk < 2; ++chunk) {
        const int ch = chunk * 32 + cg * 4;
        short* wrh = &Ah[spx * AROW + cg * 4];
        short* wrl = &Al[spx * AROW + cg * 4];
#pragma unroll
        for (int n = 0; n < 9; ++n) {
            float px_f = (float)(i + n / 3) + OFFSEL(n);
            float py_f = (float)(j + n % 3) + OFFSEL(9 + n);
            float qx = floorf(px_f), qy = floorf(py_f);
            int ltx = min(max((int)qx, 0), H - 1);
            int lty = min(max((int)qy, 0), W - 1);
            int rbx = min(max((int)qx + 1, 0), H - 1);
            int rby = min(max((int)qy + 1, 0), W - 1);
            float px = fminf(fmaxf(px_f, 0.0f), (float)(H - 1));
            float py = fminf(fmaxf(py_f, 0.0f), (float)(W - 1));
            float alt = 1.0f + ((float)ltx - px);
            float arb = 1.0f - ((float)rbx - px);
            float blt = 1.0f + ((float)lty - py);
            float brb = 1.0f - ((float)rby - py);
            float g0 = alt * blt, g1 = arb * brb, g2 = alt * brb, g3 = arb * blt;
            int slr = ltx - (i0 - 1), srr = rbx - (i0 - 1);
            int slc = lty - (j0 - 1), src = rby - (j0 - 1);
            float4 v0, v1, v2, v3;
            if (((unsigned)slr < 8u) & ((unsigned)srr < 8u) &
                ((unsigned)slc < 12u) & ((unsigned)src < 12u)) {
                v0 = *(float4*)&Xs[(slr * 12 + slc) * XROW + ch];
                v1 = *(float4*)&Xs[(srr * 12 + src) * XROW + ch];
                v2 = *(float4*)&Xs[(slr * 12 + src) * XROW + ch];
                v3 = *(float4*)&Xs[(srr * 12 + slc) * XROW + ch];
            } else {
                v0 = *(const float4*)(xb + (size_t)(ltx * W + lty) * 64 + ch);
                v1 = *(const float4*)(xb + (size_t)(rbx * W + rby) * 64 + ch);
                v2 = *(const float4*)(xb + (size_t)(ltx * W + rby) * 64 + ch);
                v3 = *(const float4*)(xb + (size_t)(rbx * W + lty) * 64 + ch);
            }
            float s0 = g0 * v0.x + g1 * v1.x + g2 * v2.x + g3 * v3.x;
            float s1 = g0 * v0.y + g1 * v1.y + g2 * v2.y + g3 * v3.y;
            float s2 = g0 * v0.z + g1 * v1.z + g2 * v2.z + g3 * v3.z;
            float s3 = g0 * v0.w + g1 * v1.w + g2 * v2.w + g3 * v3.w;
            s16x4 h4, l4;
            split_bf4(s0, s1, s2, s3, h4, l4);
            *(s16x4*)(wrh + n * 32) = h4;
            *(s16x4*)(wrl + n * 32) = l4;
        }
        __syncthreads();
        const short* aph = &Ah[(mtb * 16 + l15) * AROW + quad * 8];
        const short* apl = &Al[(mtb * 16 + l15) * AROW + quad * 8];
#pragma unroll
        for (int kt = 0; kt < 9; ++kt) {
            bf16x8 afh = *(const bf16x8*)(aph + kt * 32);
            bf16x8 afl = *(const bf16x8*)(apl + kt * 32);
#pragma unroll
            for (int nt = 0; nt < 2; ++nt) {
                int fb = ((chunk * 9 + kt) * 4 + ntb0 + nt) * 512 + lane * 8;
                bf16x8 bfh = *(const bf16x8*)(Wtdh + fb);
                bf16x8 bfl = *(const bf16x8*)(Wtdl + fb);
                acc[nt] = __builtin_amdgcn_mfma_f32_16x16x32_bf16(afh, bfh, acc[nt], 0, 0, 0);
                acc[nt] = __builtin_amdgcn_mfma_f32_16x16x32_bf16(afl, bfh, acc[nt], 0, 0, 0);
                acc[nt] = __builtin_amdgcn_mfma_f32_16x16x32_bf16(afh, bfl, acc[nt], 0, 0, 0);
            }
        }
        __syncthreads();
    }
#undef OFFSEL

    // ============ EPILOGUE: store + fused stats ============
    float* Ld = (float*)smem;
    if (OUT_NHWC) {
        int pxr = mtb * 16 + quad * 4;
#pragma unroll
        for (int nt = 0; nt < 2; ++nt) {
            int c = (ntb0 + nt) * 16 + l15;
#pragma unroll
            for (int r = 0; r < 4; ++r)
                Ld[(pxr + r) * 72 + c] = acc[nt][r];
        }
        __syncthreads();
#pragma unroll
        for (int r = 0; r < 2; ++r) {
            int px = (t >> 4) + r * 16, c4 = t & 15;
            float4 v = *(float4*)&Ld[px * 72 + c4 * 4];
            int pij = (i0 + (px >> 3)) * W + j0 + (px & 7);
            *(float4*)(out + (size_t)(b * HW + pij) * 64 + c4 * 4) = v;
        }
    } else {
        int pxr = mtb * 16 + quad * 4;
#pragma unroll
        for (int nt = 0; nt < 2; ++nt) {
            int c = (ntb0 + nt) * 16 + l15;
#pragma unroll
            for (int r = 0; r < 4; ++r)
                Ld[c * 36 + pxr + r] = acc[nt][r];
        }
        __syncthreads();
#pragma unroll
        for (int cc = 0; cc < 2; ++cc) {
            int c = cc * 32 + (t >> 3), p4 = t & 7;
            float4 v = *(float4*)&Ld[c * 36 + p4 * 4];
            int px = p4 * 4;
            int pij = (i0 + (px >> 3)) * W + j0 + (px & 7);
            *(float4*)(out + (size_t)(b * COUT + c) * HW + pij) = v;
        }
    }
    {
        float* Sr = Xs;
        int c = t & 63, g = t >> 6;
        float s = 0.f, q = 0.f;
#pragma unroll
        for (int k = 0; k < 8; ++k) {
            int px = g * 8 + k;
            float v = OUT_NHWC ? Ld[px * 72 + c] : Ld[c * 36 + px];
            s += v; q += v * v;
        }
        Sr[g * 64 + c]       = s;
        Sr[256 + g * 64 + c] = q;
        __syncthreads();
        if (t < 64) {
            float ts = Sr[t] + Sr[64 + t] + Sr[128 + t] + Sr[192 + t];
            float tq = Sr[256 + t] + Sr[320 + t] + Sr[384 + t] + Sr[448 + t];
            part[(size_t)blockIdx.x * 128 + t]      = ts;
            part[(size_t)blockIdx.x * 128 + 64 + t] = tq;
        }
    }
}

// ---------------------------------------------------------------------------
// Reduce per-block partials -> per-channel scale/shift. grid = 64.
// ---------------------------------------------------------------------------
__global__ __launch_bounds__(256) void k_stats2(const float* __restrict__ part,
                                                const float* __restrict__ gamma,
                                                const float* __restrict__ beta,
                                                float* __restrict__ ss) {
    int c = blockIdx.x, t = threadIdx.x;
    float s = 0.f, q = 0.f;
    for (int k = t; k < NBLK; k += 256) {
        s += part[(size_t)k * 128 + c];
        q += part[(size_t)k * 128 + 64 + c];
    }
#pragma unroll
    for (int d = 32; d > 0; d >>= 1) {
        s += __shfl_down(s, d, 64);
        q += __shfl_down(q, d, 64);
    }
    __shared__ float red[8];
    int wv = t >> 6;
    if ((t & 63) == 0) { red[wv] = s; red[4 + wv] = q; }
    __syncthreads();
    if (t == 0) {
        float ts = red[0] + red[1] + red[2] + red[3];
        float tq = red[4] + red[5] + red[6] + red[7];
        const float inv_m = 1.0f / (float)(BATCH * HW);
        float mu    = ts * inv_m;
        float var   = tq * inv_m - mu * mu;
        float scale = rsqrtf(var + 1e-5f) * gamma[c];
        ss[c]      = scale;
        ss[64 + c] = beta[c] - mu * scale;
    }
}

// ---------------------------------------------------------------------------
// BN+ReLU on NHWC (stage 1).
// ---------------------------------------------------------------------------
__global__ __launch_bounds__(256) void k_bnrelu_nhwc(const float* __restrict__ y,
                                                     const float* __restrict__ ss,
                                                     float* __restrict__ out) {
    size_t idx = ((size_t)blockIdx.x * 256 + threadIdx.x) * 4;
    int c4 = (int)(idx & 63);
    float4 sc = *(const float4*)(ss + c4);
    float4 sh = *(const float4*)(ss + 64 + c4);
    float4 v  = *(const float4*)(y + idx);
    float4 r;
    r.x = fmaxf(fmaf(v.x, sc.x, sh.x), 0.f);
    r.y = fmaxf(fmaf(v.y, sc.y, sh.y), 0.f);
    r.z = fmaxf(fmaf(v.z, sc.z, sh.z), 0.f);
    r.w = fmaxf(fmaf(v.w, sc.w, sh.w), 0.f);
    *(float4*)(out + idx) = r;
}

// ---------------------------------------------------------------------------
// BN+ReLU on NCHW, IN-PLACE (stage 2).
// ---------------------------------------------------------------------------
__global__ __launch_bounds__(256) void k_bnrelu_nchw(float* __restrict__ y,
                                                     const float* __restrict__ ss) {
    int c = (blockIdx.x / 49) % COUT;
    float scale = ss[c], shift = ss[64 + c];
    size_t idx = ((size_t)blockIdx.x * 1024) + threadIdx.x * 4;
    float4 v = *(const float4*)(y + idx);
    float4 r;
    r.x = fmaxf(fmaf(v.x, scale, shift), 0.f);
    r.y = fmaxf(fmaf(v.y, scale, shift), 0.f);
    r.z = fmaxf(fmaf(v.z, scale, shift), 0.f);
    r.w = fmaxf(fmaf(v.w, scale, shift), 0.f);
    *(float4*)(y + idx) = r;
}

// ---------------------------------------------------------------------------
// Workspace (~28 MB): weights 216 KB | part 1.6 MB | ss 512 B |
// bufB(xT / y1 NHWC) 25.7 MB.
// ---------------------------------------------------------------------------
extern "C" void kernel_launch(void* const* d_in, const int* in_sizes, int n_in,
                              void* d_out, int out_size, void* d_ws, size_t ws_size,
                              hipStream_t stream) {
    const float* x       = (const float*)d_in[0];
    const float* w_off1  = (const float*)d_in[1];
    const float* b_off1  = (const float*)d_in[2];
    const float* w_conv1 = (const float*)d_in[3];
    const float* gamma1  = (const float*)d_in[4];
    const float* beta1   = (const float*)d_in[5];
    const float* w_off2  = (const float*)d_in[6];
    const float* b_off2  = (const float*)d_in[7];
    const float* w_conv2 = (const float*)d_in[8];
    const float* gamma2  = (const float*)d_in[9];
    const float* beta2   = (const float*)d_in[10];
    float* out = (float*)d_out;

    char*  wsb  = (char*)d_ws;
    short* Wtdh = (short*)wsb;                           // 73728
    short* Wtdl = (short*)(wsb + 73728);                 // 73728
    short* Wtoh = (short*)(wsb + 147456);                // 36864
    short* Wtol = (short*)(wsb + 184320);                // 36864
    float* part = (float*)(wsb + 221184);                // 1605632
    float* ss   = (float*)(wsb + 1826816);               // 512
    float* bufB = (float*)(wsb + 1827328);               // xT/y1: 25690112

    const int tp_blocks = (BATCH * HW) / 64;             // 1568
    const int bn_blocks = (BATCH * COUT * HW) / 1024;    // 6272

    // ---- stage 1 ----
    k_prepw       <<<216, 256, 0, stream>>>(w_conv1, w_off1, Wtdh, Wtdl, Wtoh, Wtol);
    k_transpose   <<<tp_blocks, 256, 0, stream>>>(x, bufB);
    k_fused<true> <<<NBLK, 256, 0, stream>>>(bufB, Wtoh, Wtol, b_off1, Wtdh, Wtdl, out, part);
    k_stats2      <<<64, 256, 0, stream>>>(part, gamma1, beta1, ss);
    k_bnrelu_nhwc <<<bn_blocks, 256, 0, stream>>>(out, ss, bufB);   // y1 (NHWC)

    // ---- stage 2 ----
    k_prepw       <<<216, 256, 0, stream>>>(w_conv2, w_off2, Wtdh, Wtdl, Wtoh, Wtol);
    k_fused<false><<<NBLK, 256, 0, stream>>>(bufB, Wtoh, Wtol, b_off2, Wtdh, Wtdl, out, part);
    k_stats2      <<<64, 256, 0, stream>>>(part, gamma2, beta2, ss);
    k_bnrelu_nchw <<<bn_blocks, 256, 0, stream>>>(out, ss);         // in-place
}